// Round 13
// baseline (1479.340 us; speedup 1.0000x reference)
//
#include <hip/hip_runtime.h>

// ---------------------------------------------------------------------------
// MEASUREMENT ROUND 3 (gemm-only): exact round-7 pipeline (218us best), with
// the GEMM given an internal idempotent rep x5 so its dispatches (~830us)
// dominate the rocprof top-5. lif/readout run once (normal).
// Divide gemm dur/FETCH by 5. Everything else identical to round 7.
// ---------------------------------------------------------------------------

typedef float  f32x4  __attribute__((ext_vector_type(4)));
typedef short  short8 __attribute__((ext_vector_type(8)));
typedef unsigned long long ull;

#define B_   256
#define T_   1000
#define K_   700
#define H_   64
#define O_   20
#define NKT  22          // ceil(700/32) k-tiles of BK=32
#define NCH  200         // v_ro chunks
#define TCH  5           // chunk length (NCH*TCH = T_)
#define TCL  100         // LIF chunk length
#define NCL  10          // LIF chunks
#define BIL  40          // LIF burn-in steps

#define REP_G 5

// workspace layout (bytes)
#define OFF_WFRAG  ((size_t)0)            // 22*8192 = 180,224
#define OFF_CUR    ((size_t)262144)       // 256000*64*4 = 65,536,000
#define OFF_MASK   ((size_t)65798144)     // 256000*8    =  2,048,000

// ---------------------------------------------------------------------------
// k0: pack W_h into fragment-ordered split-bf16, BK=32 tiles (zero-pad k>=700).
// ---------------------------------------------------------------------------
__global__ void wprep(const float* __restrict__ Wh, unsigned short* __restrict__ wfrag) {
    int e = blockIdx.x * 256 + threadIdx.x;          // 22*256 = 5632 exact
    int kt   = e >> 8;
    int rem  = e & 255;
    int nf   = rem >> 6;
    int lane = rem & 63;
    int h     = nf * 16 + (lane & 15);
    int kbase = kt * 32 + ((lane >> 4) & 3) * 8;
    unsigned short* dh = wfrag + (size_t)kt * 4096 + (nf * 64 + lane) * 8;
    unsigned short* dl = dh + 2048;
#pragma unroll
    for (int j = 0; j < 8; ++j) {
        int k = kbase + j;
        float v = (k < K_) ? Wh[(size_t)h * K_ + k] : 0.0f;
        unsigned u  = __builtin_bit_cast(unsigned, v);
        float    fh = __builtin_bit_cast(float, u & 0xffff0000u);
        float    r  = v - fh;
        dh[j] = (unsigned short)(u >> 16);
        dl[j] = (unsigned short)(__builtin_bit_cast(unsigned, r) >> 16);
    }
}

// ---------------------------------------------------------------------------
// k1: GEMM (round-7 structure exactly), x REP_G internal repeats.
// ---------------------------------------------------------------------------
__device__ __forceinline__ void glds16(const void* src, void* lds) {
    __builtin_amdgcn_global_load_lds(
        (const __attribute__((address_space(1))) void*)src,
        (__attribute__((address_space(3))) void*)lds, 16, 0, 0);
}

__device__ __forceinline__ void splitpair(f32x4 p0, f32x4 p1, short8& hi, short8& lo) {
#pragma unroll
    for (int j = 0; j < 4; ++j) {
        {
            unsigned u  = __builtin_bit_cast(unsigned, p0[j]);
            float    fh = __builtin_bit_cast(float, u & 0xffff0000u);
            float    r  = p0[j] - fh;
            hi[j] = (short)(u >> 16);
            lo[j] = (short)(__builtin_bit_cast(unsigned, r) >> 16);
        }
        {
            unsigned u  = __builtin_bit_cast(unsigned, p1[j]);
            float    fh = __builtin_bit_cast(float, u & 0xffff0000u);
            float    r  = p1[j] - fh;
            hi[j + 4] = (short)(u >> 16);
            lo[j + 4] = (short)(__builtin_bit_cast(unsigned, r) >> 16);
        }
    }
}

__device__ __forceinline__ void stage_x32(const float* __restrict__ x, size_t row0,
                                          int kt, int lane, int wid, float* sbuf) {
#pragma unroll
    for (int j = 0; j < 4; ++j) {
        int c   = j * 256 + wid * 64 + lane;
        int row = c >> 3;
        int col = c & 7;
        int csw = (col ^ (row & 7)) << 4;        // pre-swizzled source col
        int kbyte = kt * 128 + csw;
        if (kbyte + 16 > K_ * 4) kbyte = 0;      // tail clamp; value * W_pad(0) = 0
        const char* src = (const char*)(x + (row0 + row) * (size_t)K_) + kbyte;
        float* dst = sbuf + (size_t)(j * 256 + wid * 64) * 4;  // wave-uniform base
        glds16(src, dst);
    }
}

__device__ __forceinline__ void stage_w32(const unsigned short* __restrict__ wfrag,
                                          int kt, int lane, int wid, unsigned short* sbuf) {
#pragma unroll
    for (int j = 0; j < 2; ++j) {
        int c = j * 256 + wid * 64 + lane;
        int l = c ^ ((c >> 4) & 7);
        const unsigned short* src = wfrag + (size_t)kt * 4096 + l * 8;
        unsigned short* dst = sbuf + (size_t)(j * 256 + wid * 64) * 8;   // wave-uniform base
        glds16(src, dst);
    }
}

__device__ __forceinline__ void compute32(const float* sbx_, const unsigned short* sbw_,
                                          int lane, int wid, f32x4 (&acc)[2][4]) {
    const f32x4*  xb = (const f32x4*)sbx_;
    const short8* wb = (const short8*)sbw_;
    short8 ah[2], al[2];
    int v0 = (lane >> 4) * 2;
#pragma unroll
    for (int i = 0; i < 2; ++i) {
        int r  = wid * 32 + i * 16 + (lane & 15);
        int c0 = r * 8 + (v0 ^ (r & 7));
        int c1 = r * 8 + ((v0 + 1) ^ (r & 7));
        splitpair(xb[c0], xb[c1], ah[i], al[i]);
    }
#pragma unroll
    for (int n = 0; n < 4; ++n) {
        int lh = n * 64 + lane;
        int ph = lh ^ ((lh >> 4) & 7);
        short8 bhf = wb[ph];
        short8 blf = wb[ph + 256];
#pragma unroll
        for (int i = 0; i < 2; ++i) {
            acc[i][n] = __builtin_amdgcn_mfma_f32_16x16x32_bf16(ah[i], bhf, acc[i][n], 0, 0, 0);
            acc[i][n] = __builtin_amdgcn_mfma_f32_16x16x32_bf16(al[i], bhf, acc[i][n], 0, 0, 0);
            acc[i][n] = __builtin_amdgcn_mfma_f32_16x16x32_bf16(ah[i], blf, acc[i][n], 0, 0, 0);
        }
    }
}

__global__ __launch_bounds__(256, 3) void gemm_cur(const float* __restrict__ x,
                                                   const unsigned short* __restrict__ wfrag,
                                                   const float* __restrict__ b_h,
                                                   float* __restrict__ cur) {
    __shared__ float          sbx[2][4096];   // 2 x 16KB x-tiles
    __shared__ unsigned short sbw[2][4096];   // 2 x  8KB W-tiles
    int tid  = threadIdx.x;
    int lane = tid & 63;
    int wid  = tid >> 6;             // 0..3
    size_t row0 = (size_t)blockIdx.x * 128;

    float bh4[4];
#pragma unroll
    for (int n = 0; n < 4; ++n) bh4[n] = b_h[n * 16 + (lane & 15)];

    for (int rep = 0; rep < REP_G; ++rep) {
        __syncthreads();             // protect LDS reuse across reps

        f32x4 acc[2][4];
#pragma unroll
        for (int i = 0; i < 2; ++i)
#pragma unroll
            for (int n = 0; n < 4; ++n) acc[i][n] = (f32x4){0.f, 0.f, 0.f, 0.f};

        stage_x32(x, row0, 0, lane, wid, sbx[0]);  stage_w32(wfrag, 0, lane, wid, sbw[0]);
        stage_x32(x, row0, 1, lane, wid, sbx[1]);  stage_w32(wfrag, 1, lane, wid, sbw[1]);

#define GSTEP(T, N)                                                          \
    {                                                                        \
        asm volatile("s_waitcnt vmcnt(" #N ")" ::: "memory");                \
        __builtin_amdgcn_s_barrier();                                        \
        compute32(sbx[(T) & 1], sbw[(T) & 1], lane, wid, acc);               \
        asm volatile("s_waitcnt lgkmcnt(0)" ::: "memory");                   \
        __builtin_amdgcn_s_barrier();                                        \
        if ((T) + 2 < NKT) {                                                 \
            stage_x32(x, row0, (T) + 2, lane, wid, sbx[(T) & 1]);            \
            stage_w32(wfrag, (T) + 2, lane, wid, sbw[(T) & 1]);              \
        }                                                                    \
    }
        GSTEP(0, 6)   GSTEP(1, 6)   GSTEP(2, 6)   GSTEP(3, 6)   GSTEP(4, 6)
        GSTEP(5, 6)   GSTEP(6, 6)   GSTEP(7, 6)   GSTEP(8, 6)   GSTEP(9, 6)
        GSTEP(10, 6)  GSTEP(11, 6)  GSTEP(12, 6)  GSTEP(13, 6)  GSTEP(14, 6)
        GSTEP(15, 6)  GSTEP(16, 6)  GSTEP(17, 6)  GSTEP(18, 6)  GSTEP(19, 6)
        GSTEP(20, 6)  GSTEP(21, 0)
#undef GSTEP

        // epilogue: t-quad layout cur4[(r>>2)*64 + h] (16B stores)
        f32x4* cur4 = (f32x4*)cur;
#pragma unroll
        for (int i = 0; i < 2; ++i) {
            size_t r4 = row0 + wid * 32 + i * 16 + ((lane >> 4) & 3) * 4;
#pragma unroll
            for (int n = 0; n < 4; ++n) {
                f32x4 q;
#pragma unroll
                for (int j = 0; j < 4; ++j) q[j] = acc[i][n][j] + bh4[n];
                cur4[(r4 >> 2) * 64 + n * 16 + (lane & 15)] = q;
            }
        }
    }
}

// ---------------------------------------------------------------------------
// k2: LIF, chunked speculative (round-7 exact). t-quad coalesced loads.
// ---------------------------------------------------------------------------
__global__ __launch_bounds__(64) void lif(const float* __restrict__ cur, ull* __restrict__ masks) {
    int b = blockIdx.x & 255;
    int c = blockIdx.x >> 8;
    int h = threadIdx.x;
    int t0 = c * TCL;
    int ts = (c == 0) ? 0 : (t0 - BIL);
    const f32x4* p = (const f32x4*)cur + (((size_t)b * T_ + ts) >> 2) * 64 + h;
    float v = 0.0f;
    int ngb = (t0 - ts) >> 2;          // burn-in groups (0 or 10)
    for (int g = 0; g < ngb; ++g) {
        f32x4 q = p[g * 64];
#pragma unroll
        for (int j = 0; j < 4; ++j) {
            v = (v + q[j]) * 0.5f;
            v = (v >= 1.0f) ? 0.0f : v;
        }
    }
    p += (size_t)ngb * 64;
    ull* mp = masks + (size_t)b * T_ + t0;
#pragma unroll 2
    for (int g = 0; g < TCL / 4; ++g) {
        f32x4 q = p[g * 64];
#pragma unroll
        for (int j = 0; j < 4; ++j) {
            v = (v + q[j]) * 0.5f;
            bool s = (v >= 1.0f);
            ull m = __ballot(s);
            if (h == 0) mp[g * 4 + j] = m;
            v = s ? 0.0f : v;
        }
    }
}

// ---------------------------------------------------------------------------
// k3: fused readout, one block per batch, 512 threads (round-7 exact).
// ---------------------------------------------------------------------------
__global__ __launch_bounds__(512) void readout(const ull* __restrict__ masks,
                                               const float* __restrict__ Wr,
                                               const float* __restrict__ br,
                                               const float* __restrict__ tau,
                                               float* __restrict__ out) {
    __shared__ __align__(16) float wt[64][20];     // wt[h][o]
    __shared__ ull  smask[T_];
    __shared__ __align__(16) float E[NCH][20];
    __shared__ __align__(16) float Sv[NCH][20];
    __shared__ __align__(16) float pacc[NCH][20];
    __shared__ __align__(16) float sScale[20], sBase[20], sBeta[20];
    __shared__ float Pg[8][20], Sst[8][20], part[8][20];

    int tid = threadIdx.x;
    int b   = blockIdx.x;
    for (int i = tid; i < 1280; i += 512) wt[i & 63][i >> 6] = Wr[(size_t)(i >> 6) * 64 + (i & 63)];
    for (int i = tid; i < T_; i += 512) smask[i] = masks[(size_t)b * T_ + i];
    if (tid < 20) {
        float beta = 1.0f / (1.0f + __expf(-tau[tid]));
        sBeta[tid]  = beta;
        sScale[tid] = 1.0f - beta;
        sBase[tid]  = br[tid];
    }
    __syncthreads();

    // phase 1: scanE — items (c, o4), NCH*5 = 1000
    for (int it = tid; it < NCH * 5; it += 512) {
        int o4 = it % 5;
        int c  = it / 5;
        f32x4 beta4  = *(const f32x4*)&sBeta[o4 * 4];
        f32x4 scale4 = *(const f32x4*)&sScale[o4 * 4];
        f32x4 base4  = *(const f32x4*)&sBase[o4 * 4];
        f32x4 v = {0.f, 0.f, 0.f, 0.f};
        const ull* mp = smask + c * TCH;
#pragma unroll
        for (int j = 0; j < TCH; ++j) {
            ull m = mp[j];
            f32x4 a = {0.f, 0.f, 0.f, 0.f};
            while (m) {
                int h = __builtin_ctzll(m);
                m &= (m - 1);
                a += *(const f32x4*)&wt[h][o4 * 4];
            }
            f32x4 q;
#pragma unroll
            for (int jj = 0; jj < 4; ++jj) q[jj] = scale4[jj] * (base4[jj] + a[jj]);
            v = beta4 * v + q;
        }
        *(f32x4*)&E[c][o4 * 4] = v;
    }
    __syncthreads();

    // phase 2a: per-(o, g) partial combine over 25 chunks
    if (tid < 160) {
        int o = tid >> 3, g = tid & 7;
        float beta = sBeta[o];
        float b2 = beta * beta;
        float bp = b2 * b2 * beta;               // beta^5
        float P = 0.0f;
        for (int c = g * 25; c < g * 25 + 25; ++c) P = bp * P + E[c][o];
        Pg[g][o] = P;
    }
    __syncthreads();

    // phase 2b: serial combine of 8 groups per o
    if (tid < 20) {
        int o = tid;
        float beta = sBeta[o];
        float b2 = beta * beta;
        float bp = b2 * b2 * beta;
        float bp25 = 1.0f;
#pragma unroll
        for (int i = 0; i < 25; ++i) bp25 *= bp;
        float s = 0.0f;
        for (int g = 0; g < 8; ++g) { Sst[g][o] = s; s = bp25 * s + Pg[g][o]; }
    }
    __syncthreads();

    // phase 2c: re-scan groups to per-chunk starts Sv
    if (tid < 160) {
        int o = tid >> 3, g = tid & 7;
        float beta = sBeta[o];
        float b2 = beta * beta;
        float bp = b2 * b2 * beta;
        float s = Sst[g][o];
        for (int c = g * 25; c < g * 25 + 25; ++c) { Sv[c][o] = s; s = bp * s + E[c][o]; }
    }
    __syncthreads();

    // phase 3: scanSoft — thread c < NCH
    if (tid < NCH) {
        int c = tid;
        float beta[20], v[20], acc[20];
#pragma unroll
        for (int o = 0; o < 20; ++o) {
            beta[o] = sBeta[o];
            v[o]   = Sv[c][o];
            acc[o] = 0.0f;
        }
        int t0 = c * TCH;
        const ull* mp = smask + t0;
#pragma unroll
        for (int j = 0; j < TCH; ++j) {
            int t = t0 + j;
            ull m = mp[j];
            f32x4 a[5];
#pragma unroll
            for (int i = 0; i < 5; ++i) a[i] = (f32x4){0.f, 0.f, 0.f, 0.f};
            while (m) {
                int h = __builtin_ctzll(m);
                m &= (m - 1);
                const f32x4* w4 = (const f32x4*)&wt[h][0];
#pragma unroll
                for (int i = 0; i < 5; ++i) a[i] += w4[i];
            }
#pragma unroll
            for (int o = 0; o < 20; ++o) {
                float q = sScale[o] * (sBase[o] + a[o >> 2][o & 3]);
                v[o] = beta[o] * v[o] + q;
            }
            if (t >= 11) {
                float mx = v[0];
#pragma unroll
                for (int o = 1; o < 20; ++o) mx = fmaxf(mx, v[o]);
                float e[20], ssum = 0.0f;
#pragma unroll
                for (int o = 0; o < 20; ++o) { e[o] = __expf(v[o] - mx); ssum += e[o]; }
                float inv = 1.0f / ssum;
#pragma unroll
                for (int o = 0; o < 20; ++o) acc[o] += e[o] * inv;
            }
        }
#pragma unroll
        for (int o = 0; o < 20; ++o) pacc[c][o] = acc[o];
    }
    __syncthreads();

    // phase 4: reduce — partials then serial-8
    if (tid < 160) {
        int o = tid >> 3, g = tid & 7;
        float s = 0.0f;
        for (int c = g * 25; c < g * 25 + 25; ++c) s += pacc[c][o];
        part[g][o] = s;
    }
    __syncthreads();
    if (tid < 20) {
        float s = 0.0f;
#pragma unroll
        for (int g = 0; g < 8; ++g) s += part[g][tid];
        out[(size_t)b * 20 + tid] = s;
    }
}

// ---------------------------------------------------------------------------
extern "C" void kernel_launch(void* const* d_in, const int* in_sizes, int n_in,
                              void* d_out, int out_size, void* d_ws, size_t ws_size,
                              hipStream_t stream) {
    const float* x   = (const float*)d_in[0];
    const float* W_h = (const float*)d_in[1];
    const float* b_h = (const float*)d_in[2];
    const float* W_r = (const float*)d_in[3];
    const float* b_r = (const float*)d_in[4];
    const float* tau = (const float*)d_in[5];

    char* ws = (char*)d_ws;
    unsigned short* wfrag = (unsigned short*)(ws + OFF_WFRAG);
    float* cur  = (float*)(ws + OFF_CUR);
    ull*   msk  = (ull*)(ws + OFF_MASK);
    float* out  = (float*)d_out;

    wprep<<<22, 256, 0, stream>>>(W_h, wfrag);
    gemm_cur<<<2000, 256, 0, stream>>>(x, wfrag, b_h, cur);
    lif<<<NCL * 256, 64, 0, stream>>>(cur, msk);
    readout<<<256, 512, 0, stream>>>(msk, W_r, b_r, tau, out);
}

// Round 14
// 242.449 us; speedup vs baseline: 6.1017x; 6.1017x over previous
//
#include <hip/hip_runtime.h>

// ---------------------------------------------------------------------------
// VanillaSFNN split pipeline; barrier-free per-wave GEMM.
//   k0 wprep  : W_h -> split bf16 hi/lo, BK=32 fragment tiles (22 x 8KB)
//   k1 gemm   : 2000 blocks x 256 thr = 4 INDEPENDENT waves. Wave owns a
//               32-row stripe: stages its own x k-tiles (4 glds -> private
//               4KB LDS ring-3, XOR swizzle), loads its W fragments into
//               REGISTERS from L2 each k-step (8 x 1KB coalesced), computes.
//               No s_barrier anywhere; per-wave counted vmcnt(12).
//               48KB LDS -> 3 blocks/CU = 12 independent wave-pipelines.
//   k2 lif    : chunked speculative scan (burn-in 40), coalesced f32x4 loads
//   k3 readout: per-batch fused scan, 512 thr
// ---------------------------------------------------------------------------

typedef float  f32x4  __attribute__((ext_vector_type(4)));
typedef short  short8 __attribute__((ext_vector_type(8)));
typedef unsigned long long ull;

#define B_   256
#define T_   1000
#define K_   700
#define H_   64
#define O_   20
#define NKT  22          // k-tiles of BK=32 (704 padded)
#define NCH  200         // readout chunks
#define TCH  5
#define TCL  100         // LIF chunk length
#define NCL  10          // LIF chunks
#define BIL  40          // LIF burn-in steps

// workspace layout (bytes)
#define OFF_WFRAG  ((size_t)0)            // 22*8192 = 180,224
#define OFF_CUR    ((size_t)262144)       // 256000*64*4 = 65,536,000
#define OFF_MASK   ((size_t)65798144)     // 256000*8    =  2,048,000

// ---------------------------------------------------------------------------
// k0: W_h -> split-bf16 fragments, BK=32 tiles. Tile kt = 4096 shorts (8KB):
// hi 256 chunks x 8, lo at +2048 shorts. slot = nf*64+lane:
// h = nf*16+(lane&15), k = kt*32 + ((lane>>4)&3)*8 + j. Zero-pad k >= 700.
// ---------------------------------------------------------------------------
__global__ void wprep(const float* __restrict__ Wh, unsigned short* __restrict__ wfrag) {
    int e = blockIdx.x * 256 + threadIdx.x;          // 22*256 = 5632 exact
    int kt   = e >> 8;
    int rem  = e & 255;
    int nf   = rem >> 6;
    int lane = rem & 63;
    int h     = nf * 16 + (lane & 15);
    int kbase = kt * 32 + ((lane >> 4) & 3) * 8;
    unsigned short* dh = wfrag + (size_t)kt * 4096 + (nf * 64 + lane) * 8;
    unsigned short* dl = dh + 2048;
#pragma unroll
    for (int j = 0; j < 8; ++j) {
        int k = kbase + j;
        float v = (k < K_) ? Wh[(size_t)h * K_ + k] : 0.0f;
        unsigned u  = __builtin_bit_cast(unsigned, v);
        float    fh = __builtin_bit_cast(float, u & 0xffff0000u);
        float    r  = v - fh;
        dh[j] = (unsigned short)(u >> 16);
        dl[j] = (unsigned short)(__builtin_bit_cast(unsigned, r) >> 16);
    }
}

// ---------------------------------------------------------------------------
// k1 helpers
// ---------------------------------------------------------------------------
__device__ __forceinline__ void glds16(const void* src, void* lds) {
    __builtin_amdgcn_global_load_lds(
        (const __attribute__((address_space(1))) void*)src,
        (__attribute__((address_space(3))) void*)lds, 16, 0, 0);
}

__device__ __forceinline__ void splitpair(f32x4 p0, f32x4 p1, short8& hi, short8& lo) {
#pragma unroll
    for (int j = 0; j < 4; ++j) {
        {
            unsigned u  = __builtin_bit_cast(unsigned, p0[j]);
            float    fh = __builtin_bit_cast(float, u & 0xffff0000u);
            float    r  = p0[j] - fh;
            hi[j] = (short)(u >> 16);
            lo[j] = (short)(__builtin_bit_cast(unsigned, r) >> 16);
        }
        {
            unsigned u  = __builtin_bit_cast(unsigned, p1[j]);
            float    fh = __builtin_bit_cast(float, u & 0xffff0000u);
            float    r  = p1[j] - fh;
            hi[j + 4] = (short)(u >> 16);
            lo[j + 4] = (short)(__builtin_bit_cast(unsigned, r) >> 16);
        }
    }
}

// ---------------------------------------------------------------------------
// k1: barrier-free GEMM. Wave = 32-row stripe; W fragments in regs per step.
// ---------------------------------------------------------------------------
__global__ __launch_bounds__(256, 3) void gemm_cur(const float* __restrict__ x,
                                                   const unsigned short* __restrict__ wfrag,
                                                   const float* __restrict__ b_h,
                                                   float* __restrict__ cur) {
    __shared__ float sbx[4][3][1024];    // per-wave private ring-3 (4KB each)
    int tid  = threadIdx.x;
    int lane = tid & 63;
    int wid  = tid >> 6;                 // 0..3: row-stripe
    size_t row0 = (size_t)blockIdx.x * 128 + wid * 32;

    float* const rb0 = &sbx[wid][0][0];
    float* const rb1 = &sbx[wid][1][0];
    float* const rb2 = &sbx[wid][2][0];
    float* const ring[3] = {rb0, rb1, rb2};

    const short8* wf8 = (const short8*)wfrag;   // kt*512 chunks; hi n*64+lane, lo +256

    float bh4[4];
#pragma unroll
    for (int n = 0; n < 4; ++n) bh4[n] = b_h[n * 16 + (lane & 15)];

    f32x4 acc[2][4];
#pragma unroll
    for (int i = 0; i < 2; ++i)
#pragma unroll
        for (int n = 0; n < 4; ++n) acc[i][n] = (f32x4){0.f, 0.f, 0.f, 0.f};

    // stage this wave's 32-row x tile for k-step kt into buf
#define STAGE(KT, BUF)                                                        \
    {                                                                         \
        _Pragma("unroll")                                                     \
        for (int g = 0; g < 4; ++g) {                                         \
            int c   = g * 64 + lane;                                          \
            int row = c >> 3;                                                 \
            int pc  = c & 7;                                                  \
            int kbyte = (KT) * 128 + ((pc ^ (row & 7)) << 4);                 \
            if (kbyte + 16 > K_ * 4) kbyte = 0;                               \
            const char* src = (const char*)(x + (row0 + row) * (size_t)K_) + kbyte; \
            glds16(src, (char*)(BUF) + g * 1024);                             \
        }                                                                     \
    }

#define LOADW(KT, WREG)                                                       \
    {                                                                         \
        _Pragma("unroll")                                                     \
        for (int n = 0; n < 4; ++n) {                                         \
            WREG[n]     = wf8[(size_t)(KT) * 512 + n * 64 + lane];            \
            WREG[4 + n] = wf8[(size_t)(KT) * 512 + 256 + n * 64 + lane];      \
        }                                                                     \
    }

    int g2 = ((lane >> 4) & 3) * 2;

#define COMPUTE(BUF, WREG)                                                    \
    {                                                                         \
        const f32x4* xb = (const f32x4*)(BUF);                                \
        short8 ah[2], al[2];                                                  \
        _Pragma("unroll")                                                     \
        for (int i = 0; i < 2; ++i) {                                         \
            int r  = i * 16 + (lane & 15);                                    \
            int c0 = r * 8 + (g2 ^ (r & 7));                                  \
            int c1 = r * 8 + ((g2 + 1) ^ (r & 7));                            \
            splitpair(xb[c0], xb[c1], ah[i], al[i]);                          \
        }                                                                     \
        _Pragma("unroll")                                                     \
        for (int n = 0; n < 4; ++n) {                                         \
            _Pragma("unroll")                                                 \
            for (int i = 0; i < 2; ++i) {                                     \
                acc[i][n] = __builtin_amdgcn_mfma_f32_16x16x32_bf16(ah[i], WREG[n],     acc[i][n], 0, 0, 0); \
                acc[i][n] = __builtin_amdgcn_mfma_f32_16x16x32_bf16(al[i], WREG[n],     acc[i][n], 0, 0, 0); \
                acc[i][n] = __builtin_amdgcn_mfma_f32_16x16x32_bf16(ah[i], WREG[4 + n], acc[i][n], 0, 0, 0); \
            }                                                                 \
        }                                                                     \
    }

    short8 wcA[8], wcB[8];

    // prologue
    STAGE(0, rb0)
    STAGE(1, rb1)
    LOADW(0, wcA)

    // GSTEP(KT, vmcnt, WCUR, WNEXT): load W(KT+1), stage x(KT+2), wait, compute
#define GSTEP(KT, N, WCUR, WNEXT)                                             \
    {                                                                         \
        if ((KT) + 1 < NKT) LOADW((KT) + 1, WNEXT)                            \
        if ((KT) + 2 < NKT) STAGE((KT) + 2, ring[((KT) + 2) % 3])             \
        asm volatile("s_waitcnt vmcnt(" #N ")" ::: "memory");                 \
        COMPUTE(ring[(KT) % 3], WCUR)                                         \
    }
    GSTEP(0, 12, wcA, wcB)   GSTEP(1, 12, wcB, wcA)   GSTEP(2, 12, wcA, wcB)
    GSTEP(3, 12, wcB, wcA)   GSTEP(4, 12, wcA, wcB)   GSTEP(5, 12, wcB, wcA)
    GSTEP(6, 12, wcA, wcB)   GSTEP(7, 12, wcB, wcA)   GSTEP(8, 12, wcA, wcB)
    GSTEP(9, 12, wcB, wcA)   GSTEP(10, 12, wcA, wcB)  GSTEP(11, 12, wcB, wcA)
    GSTEP(12, 12, wcA, wcB)  GSTEP(13, 12, wcB, wcA)  GSTEP(14, 12, wcA, wcB)
    GSTEP(15, 12, wcB, wcA)  GSTEP(16, 12, wcA, wcB)  GSTEP(17, 12, wcB, wcA)
    GSTEP(18, 12, wcA, wcB)  GSTEP(19, 12, wcB, wcA)  GSTEP(20, 8, wcA, wcB)
    GSTEP(21, 0, wcB, wcA)
#undef GSTEP
#undef COMPUTE
#undef LOADW
#undef STAGE

    // epilogue: t-quad layout cur4[(r>>2)*64 + h] (16B stores), same as r7
    f32x4* cur4 = (f32x4*)cur;
#pragma unroll
    for (int i = 0; i < 2; ++i) {
        size_t r4 = row0 + i * 16 + ((lane >> 4) & 3) * 4;
#pragma unroll
        for (int n = 0; n < 4; ++n) {
            f32x4 q;
#pragma unroll
            for (int j = 0; j < 4; ++j) q[j] = acc[i][n][j] + bh4[n];
            cur4[(r4 >> 2) * 64 + n * 16 + (lane & 15)] = q;
        }
    }
}

// ---------------------------------------------------------------------------
// k2: LIF, chunked speculative. One wave per (batch, chunk); lane = neuron.
// ---------------------------------------------------------------------------
__global__ __launch_bounds__(64) void lif(const float* __restrict__ cur, ull* __restrict__ masks) {
    int b = blockIdx.x & 255;
    int c = blockIdx.x >> 8;
    int h = threadIdx.x;
    int t0 = c * TCL;
    int ts = (c == 0) ? 0 : (t0 - BIL);
    const f32x4* p = (const f32x4*)cur + (((size_t)b * T_ + ts) >> 2) * 64 + h;
    float v = 0.0f;
    int ngb = (t0 - ts) >> 2;          // burn-in groups (0 or 10)
    for (int g = 0; g < ngb; ++g) {
        f32x4 q = p[g * 64];
#pragma unroll
        for (int j = 0; j < 4; ++j) {
            v = (v + q[j]) * 0.5f;
            v = (v >= 1.0f) ? 0.0f : v;
        }
    }
    p += (size_t)ngb * 64;
    ull* mp = masks + (size_t)b * T_ + t0;
#pragma unroll 2
    for (int g = 0; g < TCL / 4; ++g) {
        f32x4 q = p[g * 64];
#pragma unroll
        for (int j = 0; j < 4; ++j) {
            v = (v + q[j]) * 0.5f;
            bool s = (v >= 1.0f);
            ull m = __ballot(s);
            if (h == 0) mp[g * 4 + j] = m;
            v = s ? 0.0f : v;
        }
    }
}

// ---------------------------------------------------------------------------
// k3: fused readout, one block per batch, 512 threads (8 waves).
// ---------------------------------------------------------------------------
__global__ __launch_bounds__(512) void readout(const ull* __restrict__ masks,
                                               const float* __restrict__ Wr,
                                               const float* __restrict__ br,
                                               const float* __restrict__ tau,
                                               float* __restrict__ out) {
    __shared__ __align__(16) float wt[64][20];     // wt[h][o]
    __shared__ ull  smask[T_];
    __shared__ __align__(16) float E[NCH][20];
    __shared__ __align__(16) float Sv[NCH][20];
    __shared__ __align__(16) float pacc[NCH][20];
    __shared__ __align__(16) float sScale[20], sBase[20], sBeta[20];
    __shared__ float Pg[8][20], Sst[8][20], part[8][20];

    int tid = threadIdx.x;
    int b   = blockIdx.x;
    for (int i = tid; i < 1280; i += 512) wt[i & 63][i >> 6] = Wr[(size_t)(i >> 6) * 64 + (i & 63)];
    for (int i = tid; i < T_; i += 512) smask[i] = masks[(size_t)b * T_ + i];
    if (tid < 20) {
        float beta = 1.0f / (1.0f + __expf(-tau[tid]));
        sBeta[tid]  = beta;
        sScale[tid] = 1.0f - beta;
        sBase[tid]  = br[tid];
    }
    __syncthreads();

    // phase 1: scanE — items (c, o4), NCH*5 = 1000
    for (int it = tid; it < NCH * 5; it += 512) {
        int o4 = it % 5;
        int c  = it / 5;
        f32x4 beta4  = *(const f32x4*)&sBeta[o4 * 4];
        f32x4 scale4 = *(const f32x4*)&sScale[o4 * 4];
        f32x4 base4  = *(const f32x4*)&sBase[o4 * 4];
        f32x4 v = {0.f, 0.f, 0.f, 0.f};
        const ull* mp = smask + c * TCH;
#pragma unroll
        for (int j = 0; j < TCH; ++j) {
            ull m = mp[j];
            f32x4 a = {0.f, 0.f, 0.f, 0.f};
            while (m) {
                int h = __builtin_ctzll(m);
                m &= (m - 1);
                a += *(const f32x4*)&wt[h][o4 * 4];
            }
            f32x4 q;
#pragma unroll
            for (int jj = 0; jj < 4; ++jj) q[jj] = scale4[jj] * (base4[jj] + a[jj]);
            v = beta4 * v + q;
        }
        *(f32x4*)&E[c][o4 * 4] = v;
    }
    __syncthreads();

    // phase 2a: per-(o, g) partial combine over 25 chunks
    if (tid < 160) {
        int o = tid >> 3, g = tid & 7;
        float beta = sBeta[o];
        float b2 = beta * beta;
        float bp = b2 * b2 * beta;               // beta^5
        float P = 0.0f;
        for (int c = g * 25; c < g * 25 + 25; ++c) P = bp * P + E[c][o];
        Pg[g][o] = P;
    }
    __syncthreads();

    // phase 2b: serial combine of 8 groups per o
    if (tid < 20) {
        int o = tid;
        float beta = sBeta[o];
        float b2 = beta * beta;
        float bp = b2 * b2 * beta;
        float bp25 = 1.0f;
#pragma unroll
        for (int i = 0; i < 25; ++i) bp25 *= bp;
        float s = 0.0f;
        for (int g = 0; g < 8; ++g) { Sst[g][o] = s; s = bp25 * s + Pg[g][o]; }
    }
    __syncthreads();

    // phase 2c: re-scan groups to per-chunk starts Sv
    if (tid < 160) {
        int o = tid >> 3, g = tid & 7;
        float beta = sBeta[o];
        float b2 = beta * beta;
        float bp = b2 * b2 * beta;
        float s = Sst[g][o];
        for (int c = g * 25; c < g * 25 + 25; ++c) { Sv[c][o] = s; s = bp * s + E[c][o]; }
    }
    __syncthreads();

    // phase 3: scanSoft — thread c < NCH
    if (tid < NCH) {
        int c = tid;
        float beta[20], v[20], acc[20];
#pragma unroll
        for (int o = 0; o < 20; ++o) {
            beta[o] = sBeta[o];
            v[o]   = Sv[c][o];
            acc[o] = 0.0f;
        }
        int t0 = c * TCH;
        const ull* mp = smask + t0;
#pragma unroll
        for (int j = 0; j < TCH; ++j) {
            int t = t0 + j;
            ull m = mp[j];
            f32x4 a[5];
#pragma unroll
            for (int i = 0; i < 5; ++i) a[i] = (f32x4){0.f, 0.f, 0.f, 0.f};
            while (m) {
                int h = __builtin_ctzll(m);
                m &= (m - 1);
                const f32x4* w4 = (const f32x4*)&wt[h][0];
#pragma unroll
                for (int i = 0; i < 5; ++i) a[i] += w4[i];
            }
#pragma unroll
            for (int o = 0; o < 20; ++o) {
                float q = sScale[o] * (sBase[o] + a[o >> 2][o & 3]);
                v[o] = beta[o] * v[o] + q;
            }
            if (t >= 11) {
                float mx = v[0];
#pragma unroll
                for (int o = 1; o < 20; ++o) mx = fmaxf(mx, v[o]);
                float e[20], ssum = 0.0f;
#pragma unroll
                for (int o = 0; o < 20; ++o) { e[o] = __expf(v[o] - mx); ssum += e[o]; }
                float inv = 1.0f / ssum;
#pragma unroll
                for (int o = 0; o < 20; ++o) acc[o] += e[o] * inv;
            }
        }
#pragma unroll
        for (int o = 0; o < 20; ++o) pacc[c][o] = acc[o];
    }
    __syncthreads();

    // phase 4: reduce — partials then serial-8
    if (tid < 160) {
        int o = tid >> 3, g = tid & 7;
        float s = 0.0f;
        for (int c = g * 25; c < g * 25 + 25; ++c) s += pacc[c][o];
        part[g][o] = s;
    }
    __syncthreads();
    if (tid < 20) {
        float s = 0.0f;
#pragma unroll
        for (int g = 0; g < 8; ++g) s += part[g][tid];
        out[(size_t)b * 20 + tid] = s;
    }
}

// ---------------------------------------------------------------------------
extern "C" void kernel_launch(void* const* d_in, const int* in_sizes, int n_in,
                              void* d_out, int out_size, void* d_ws, size_t ws_size,
                              hipStream_t stream) {
    const float* x   = (const float*)d_in[0];
    const float* W_h = (const float*)d_in[1];
    const float* b_h = (const float*)d_in[2];
    const float* W_r = (const float*)d_in[3];
    const float* b_r = (const float*)d_in[4];
    const float* tau = (const float*)d_in[5];

    char* ws = (char*)d_ws;
    unsigned short* wfrag = (unsigned short*)(ws + OFF_WFRAG);
    float* cur  = (float*)(ws + OFF_CUR);
    ull*   msk  = (ull*)(ws + OFF_MASK);
    float* out  = (float*)d_out;

    wprep<<<22, 256, 0, stream>>>(W_h, wfrag);
    gemm_cur<<<2000, 256, 0, stream>>>(x, wfrag, b_h, cur);
    lif<<<NCL * 256, 64, 0, stream>>>(cur, msk);
    readout<<<256, 512, 0, stream>>>(msk, W_r, b_r, tau, out);
}

// Round 15
// 229.957 us; speedup vs baseline: 6.4331x; 1.0543x over previous
//
#include <hip/hip_runtime.h>

// ---------------------------------------------------------------------------
// VanillaSFNN split pipeline (r7 schedule) with high-occupancy gemm.
//   k0 wprep  : W_h -> split bf16 hi/lo, BK=32 fragment tiles (22 x 8KB)
//   k1 gemm   : 4000 blocks x 256 thr (4 waves), BM=64, BK=32, ring-2,
//               counted vmcnt(4); 32KB LDS -> 5 blocks/CU (20 waves/CU).
//               Wave = 1 m-frag x 4 n-frags. cur in t-quad layout.
//   k2 lif    : chunked speculative scan (burn-in 40), coalesced f32x4 loads
//   k3 readout: per-batch fused scan, 512 thr
// ---------------------------------------------------------------------------

typedef float  f32x4  __attribute__((ext_vector_type(4)));
typedef short  short8 __attribute__((ext_vector_type(8)));
typedef unsigned long long ull;

#define B_   256
#define T_   1000
#define K_   700
#define H_   64
#define O_   20
#define NKT  22          // k-tiles of BK=32 (704 padded)
#define NCH  200         // readout chunks
#define TCH  5
#define TCL  100         // LIF chunk length
#define NCL  10          // LIF chunks
#define BIL  40          // LIF burn-in steps

// workspace layout (bytes)
#define OFF_WFRAG  ((size_t)0)            // 22*8192 = 180,224
#define OFF_CUR    ((size_t)262144)       // 256000*64*4 = 65,536,000
#define OFF_MASK   ((size_t)65798144)     // 256000*8    =  2,048,000

// ---------------------------------------------------------------------------
// k0: W_h -> split-bf16 fragments, BK=32 tiles. Tile kt = 4096 shorts (8KB):
// hi 256 chunks x 8, lo at +2048 shorts. slot = nf*64+lane:
// h = nf*16+(lane&15), k = kt*32 + ((lane>>4)&3)*8 + j. Zero-pad k >= 700.
// ---------------------------------------------------------------------------
__global__ void wprep(const float* __restrict__ Wh, unsigned short* __restrict__ wfrag) {
    int e = blockIdx.x * 256 + threadIdx.x;          // 22*256 = 5632 exact
    int kt   = e >> 8;
    int rem  = e & 255;
    int nf   = rem >> 6;
    int lane = rem & 63;
    int h     = nf * 16 + (lane & 15);
    int kbase = kt * 32 + ((lane >> 4) & 3) * 8;
    unsigned short* dh = wfrag + (size_t)kt * 4096 + (nf * 64 + lane) * 8;
    unsigned short* dl = dh + 2048;
#pragma unroll
    for (int j = 0; j < 8; ++j) {
        int k = kbase + j;
        float v = (k < K_) ? Wh[(size_t)h * K_ + k] : 0.0f;
        unsigned u  = __builtin_bit_cast(unsigned, v);
        float    fh = __builtin_bit_cast(float, u & 0xffff0000u);
        float    r  = v - fh;
        dh[j] = (unsigned short)(u >> 16);
        dl[j] = (unsigned short)(__builtin_bit_cast(unsigned, r) >> 16);
    }
}

// ---------------------------------------------------------------------------
// k1 helpers
// ---------------------------------------------------------------------------
__device__ __forceinline__ void glds16(const void* src, void* lds) {
    __builtin_amdgcn_global_load_lds(
        (const __attribute__((address_space(1))) void*)src,
        (__attribute__((address_space(3))) void*)lds, 16, 0, 0);
}

__device__ __forceinline__ void splitpair(f32x4 p0, f32x4 p1, short8& hi, short8& lo) {
#pragma unroll
    for (int j = 0; j < 4; ++j) {
        {
            unsigned u  = __builtin_bit_cast(unsigned, p0[j]);
            float    fh = __builtin_bit_cast(float, u & 0xffff0000u);
            float    r  = p0[j] - fh;
            hi[j] = (short)(u >> 16);
            lo[j] = (short)(__builtin_bit_cast(unsigned, r) >> 16);
        }
        {
            unsigned u  = __builtin_bit_cast(unsigned, p1[j]);
            float    fh = __builtin_bit_cast(float, u & 0xffff0000u);
            float    r  = p1[j] - fh;
            hi[j + 4] = (short)(u >> 16);
            lo[j + 4] = (short)(__builtin_bit_cast(unsigned, r) >> 16);
        }
    }
}

// stage one x-tile: 64 rows x 32 k = 8KB = 512 chunks; 2 glds/thread.
// LDS phys (row, pc) holds logical chunk pc ^ (row&7) -> source pre-swizzled.
__device__ __forceinline__ void stage_x32(const float* __restrict__ x, size_t row0,
                                          int kt, int tid, float* sbuf) {
#pragma unroll
    for (int j = 0; j < 2; ++j) {
        int c   = j * 256 + tid;                 // 0..511
        int row = c >> 3;
        int pc  = c & 7;
        int kbyte = kt * 128 + ((pc ^ (row & 7)) << 4);
        if (kbyte + 16 > K_ * 4) kbyte = 0;      // tail clamp; value * W_pad(0) = 0
        const char* src = (const char*)(x + (row0 + row) * (size_t)K_) + kbyte;
        float* dst = sbuf + (size_t)(c & ~63) * 4;   // wave-uniform base + lane*16B
        glds16(src, dst);
    }
}

// stage one W-tile: 8KB = 512 chunks; LDS phys chunk c holds logical
// c ^ ((c>>4)&7) (involution) -> source pre-swizzled.
__device__ __forceinline__ void stage_w32(const unsigned short* __restrict__ wfrag,
                                          int kt, int tid, unsigned short* sbuf) {
#pragma unroll
    for (int j = 0; j < 2; ++j) {
        int c = j * 256 + tid;
        int l = c ^ ((c >> 4) & 7);
        const unsigned short* src = wfrag + (size_t)kt * 4096 + l * 8;
        unsigned short* dst = sbuf + (size_t)(c & ~63) * 8;   // wave-uniform base
        glds16(src, dst);
    }
}

__device__ __forceinline__ void compute32(const float* sbx_, const unsigned short* sbw_,
                                          int lane, int wid, f32x4 (&acc)[4]) {
    const f32x4*  xb = (const f32x4*)sbx_;
    const short8* wb = (const short8*)sbw_;
    int g2 = ((lane >> 4) & 3) * 2;
    int r  = wid * 16 + (lane & 15);             // row in 64-row tile
    int c0 = r * 8 + (g2 ^ (r & 7));
    int c1 = r * 8 + ((g2 + 1) ^ (r & 7));
    short8 ah, al;
    splitpair(xb[c0], xb[c1], ah, al);
#pragma unroll
    for (int n = 0; n < 4; ++n) {
        int lh = n * 64 + lane;
        int ph = lh ^ ((lh >> 4) & 7);
        short8 bhf = wb[ph];
        short8 blf = wb[ph + 256];
        acc[n] = __builtin_amdgcn_mfma_f32_16x16x32_bf16(ah, bhf, acc[n], 0, 0, 0);
        acc[n] = __builtin_amdgcn_mfma_f32_16x16x32_bf16(al, bhf, acc[n], 0, 0, 0);
        acc[n] = __builtin_amdgcn_mfma_f32_16x16x32_bf16(ah, blf, acc[n], 0, 0, 0);
    }
}

__global__ __launch_bounds__(256, 5) void gemm_cur(const float* __restrict__ x,
                                                   const unsigned short* __restrict__ wfrag,
                                                   const float* __restrict__ b_h,
                                                   float* __restrict__ cur) {
    __shared__ float          sbx[2][2048];   // 2 x 8KB x-tiles
    __shared__ unsigned short sbw[2][4096];   // 2 x 8KB W-tiles
    int tid  = threadIdx.x;
    int lane = tid & 63;
    int wid  = tid >> 6;             // 0..3: m-frag
    size_t row0 = (size_t)blockIdx.x * 64;

    float bh4[4];
#pragma unroll
    for (int n = 0; n < 4; ++n) bh4[n] = b_h[n * 16 + (lane & 15)];

    f32x4 acc[4];
#pragma unroll
    for (int n = 0; n < 4; ++n) acc[n] = (f32x4){0.f, 0.f, 0.f, 0.f};

    // prologue: stage tiles 0,1 (4 glds/thread each -> 8 outstanding)
    stage_x32(x, row0, 0, tid, sbx[0]);  stage_w32(wfrag, 0, tid, sbw[0]);
    stage_x32(x, row0, 1, tid, sbx[1]);  stage_w32(wfrag, 1, tid, sbw[1]);

#define GSTEP(T, N)                                                          \
    {                                                                        \
        asm volatile("s_waitcnt vmcnt(" #N ")" ::: "memory");                \
        __builtin_amdgcn_s_barrier();                                        \
        compute32(sbx[(T) & 1], sbw[(T) & 1], lane, wid, acc);               \
        asm volatile("s_waitcnt lgkmcnt(0)" ::: "memory");                   \
        __builtin_amdgcn_s_barrier();                                        \
        if ((T) + 2 < NKT) {                                                 \
            stage_x32(x, row0, (T) + 2, tid, sbx[(T) & 1]);                  \
            stage_w32(wfrag, (T) + 2, tid, sbw[(T) & 1]);                    \
        }                                                                    \
    }
    GSTEP(0, 4)   GSTEP(1, 4)   GSTEP(2, 4)   GSTEP(3, 4)   GSTEP(4, 4)
    GSTEP(5, 4)   GSTEP(6, 4)   GSTEP(7, 4)   GSTEP(8, 4)   GSTEP(9, 4)
    GSTEP(10, 4)  GSTEP(11, 4)  GSTEP(12, 4)  GSTEP(13, 4)  GSTEP(14, 4)
    GSTEP(15, 4)  GSTEP(16, 4)  GSTEP(17, 4)  GSTEP(18, 4)  GSTEP(19, 4)
    GSTEP(20, 4)  GSTEP(21, 0)
#undef GSTEP

    // epilogue: t-quad layout cur4[(r>>2)*64 + h] (16B stores)
    f32x4* cur4 = (f32x4*)cur;
    size_t r4 = row0 + wid * 16 + ((lane >> 4) & 3) * 4;
#pragma unroll
    for (int n = 0; n < 4; ++n) {
        f32x4 q;
#pragma unroll
        for (int j = 0; j < 4; ++j) q[j] = acc[n][j] + bh4[n];
        cur4[(r4 >> 2) * 64 + n * 16 + (lane & 15)] = q;
    }
}

// ---------------------------------------------------------------------------
// k2: LIF, chunked speculative. One wave per (batch, chunk); lane = neuron.
// t-quad cur layout: lane h loads f32x4 = 4 consecutive t's (coalesced).
// ---------------------------------------------------------------------------
__global__ __launch_bounds__(64) void lif(const float* __restrict__ cur, ull* __restrict__ masks) {
    int b = blockIdx.x & 255;
    int c = blockIdx.x >> 8;
    int h = threadIdx.x;
    int t0 = c * TCL;
    int ts = (c == 0) ? 0 : (t0 - BIL);
    const f32x4* p = (const f32x4*)cur + (((size_t)b * T_ + ts) >> 2) * 64 + h;
    float v = 0.0f;
    int ngb = (t0 - ts) >> 2;          // burn-in groups (0 or 10)
    for (int g = 0; g < ngb; ++g) {
        f32x4 q = p[g * 64];
#pragma unroll
        for (int j = 0; j < 4; ++j) {
            v = (v + q[j]) * 0.5f;
            v = (v >= 1.0f) ? 0.0f : v;
        }
    }
    p += (size_t)ngb * 64;
    ull* mp = masks + (size_t)b * T_ + t0;
#pragma unroll 2
    for (int g = 0; g < TCL / 4; ++g) {
        f32x4 q = p[g * 64];
#pragma unroll
        for (int j = 0; j < 4; ++j) {
            v = (v + q[j]) * 0.5f;
            bool s = (v >= 1.0f);
            ull m = __ballot(s);
            if (h == 0) mp[g * 4 + j] = m;
            v = s ? 0.0f : v;
        }
    }
}

// ---------------------------------------------------------------------------
// k3: fused readout, one block per batch, 512 threads (8 waves).
// ---------------------------------------------------------------------------
__global__ __launch_bounds__(512) void readout(const ull* __restrict__ masks,
                                               const float* __restrict__ Wr,
                                               const float* __restrict__ br,
                                               const float* __restrict__ tau,
                                               float* __restrict__ out) {
    __shared__ __align__(16) float wt[64][20];     // wt[h][o]
    __shared__ ull  smask[T_];
    __shared__ __align__(16) float E[NCH][20];
    __shared__ __align__(16) float Sv[NCH][20];
    __shared__ __align__(16) float pacc[NCH][20];
    __shared__ __align__(16) float sScale[20], sBase[20], sBeta[20];
    __shared__ float Pg[8][20], Sst[8][20], part[8][20];

    int tid = threadIdx.x;
    int b   = blockIdx.x;
    for (int i = tid; i < 1280; i += 512) wt[i & 63][i >> 6] = Wr[(size_t)(i >> 6) * 64 + (i & 63)];
    for (int i = tid; i < T_; i += 512) smask[i] = masks[(size_t)b * T_ + i];
    if (tid < 20) {
        float beta = 1.0f / (1.0f + __expf(-tau[tid]));
        sBeta[tid]  = beta;
        sScale[tid] = 1.0f - beta;
        sBase[tid]  = br[tid];
    }
    __syncthreads();

    // phase 1: scanE — items (c, o4), NCH*5 = 1000
    for (int it = tid; it < NCH * 5; it += 512) {
        int o4 = it % 5;
        int c  = it / 5;
        f32x4 beta4  = *(const f32x4*)&sBeta[o4 * 4];
        f32x4 scale4 = *(const f32x4*)&sScale[o4 * 4];
        f32x4 base4  = *(const f32x4*)&sBase[o4 * 4];
        f32x4 v = {0.f, 0.f, 0.f, 0.f};
        const ull* mp = smask + c * TCH;
#pragma unroll
        for (int j = 0; j < TCH; ++j) {
            ull m = mp[j];
            f32x4 a = {0.f, 0.f, 0.f, 0.f};
            while (m) {
                int h = __builtin_ctzll(m);
                m &= (m - 1);
                a += *(const f32x4*)&wt[h][o4 * 4];
            }
            f32x4 q;
#pragma unroll
            for (int jj = 0; jj < 4; ++jj) q[jj] = scale4[jj] * (base4[jj] + a[jj]);
            v = beta4 * v + q;
        }
        *(f32x4*)&E[c][o4 * 4] = v;
    }
    __syncthreads();

    // phase 2a: per-(o, g) partial combine over 25 chunks
    if (tid < 160) {
        int o = tid >> 3, g = tid & 7;
        float beta = sBeta[o];
        float b2 = beta * beta;
        float bp = b2 * b2 * beta;               // beta^5
        float P = 0.0f;
        for (int c = g * 25; c < g * 25 + 25; ++c) P = bp * P + E[c][o];
        Pg[g][o] = P;
    }
    __syncthreads();

    // phase 2b: serial combine of 8 groups per o
    if (tid < 20) {
        int o = tid;
        float beta = sBeta[o];
        float b2 = beta * beta;
        float bp = b2 * b2 * beta;
        float bp25 = 1.0f;
#pragma unroll
        for (int i = 0; i < 25; ++i) bp25 *= bp;
        float s = 0.0f;
        for (int g = 0; g < 8; ++g) { Sst[g][o] = s; s = bp25 * s + Pg[g][o]; }
    }
    __syncthreads();

    // phase 2c: re-scan groups to per-chunk starts Sv
    if (tid < 160) {
        int o = tid >> 3, g = tid & 7;
        float beta = sBeta[o];
        float b2 = beta * beta;
        float bp = b2 * b2 * beta;
        float s = Sst[g][o];
        for (int c = g * 25; c < g * 25 + 25; ++c) { Sv[c][o] = s; s = bp * s + E[c][o]; }
    }
    __syncthreads();

    // phase 3: scanSoft — thread c < NCH
    if (tid < NCH) {
        int c = tid;
        float beta[20], v[20], acc[20];
#pragma unroll
        for (int o = 0; o < 20; ++o) {
            beta[o] = sBeta[o];
            v[o]   = Sv[c][o];
            acc[o] = 0.0f;
        }
        int t0 = c * TCH;
        const ull* mp = smask + t0;
#pragma unroll
        for (int j = 0; j < TCH; ++j) {
            int t = t0 + j;
            ull m = mp[j];
            f32x4 a[5];
#pragma unroll
            for (int i = 0; i < 5; ++i) a[i] = (f32x4){0.f, 0.f, 0.f, 0.f};
            while (m) {
                int h = __builtin_ctzll(m);
                m &= (m - 1);
                const f32x4* w4 = (const f32x4*)&wt[h][0];
#pragma unroll
                for (int i = 0; i < 5; ++i) a[i] += w4[i];
            }
#pragma unroll
            for (int o = 0; o < 20; ++o) {
                float q = sScale[o] * (sBase[o] + a[o >> 2][o & 3]);
                v[o] = beta[o] * v[o] + q;
            }
            if (t >= 11) {
                float mx = v[0];
#pragma unroll
                for (int o = 1; o < 20; ++o) mx = fmaxf(mx, v[o]);
                float e[20], ssum = 0.0f;
#pragma unroll
                for (int o = 0; o < 20; ++o) { e[o] = __expf(v[o] - mx); ssum += e[o]; }
                float inv = 1.0f / ssum;
#pragma unroll
                for (int o = 0; o < 20; ++o) acc[o] += e[o] * inv;
            }
        }
#pragma unroll
        for (int o = 0; o < 20; ++o) pacc[c][o] = acc[o];
    }
    __syncthreads();

    // phase 4: reduce — partials then serial-8
    if (tid < 160) {
        int o = tid >> 3, g = tid & 7;
        float s = 0.0f;
        for (int c = g * 25; c < g * 25 + 25; ++c) s += pacc[c][o];
        part[g][o] = s;
    }
    __syncthreads();
    if (tid < 20) {
        float s = 0.0f;
#pragma unroll
        for (int g = 0; g < 8; ++g) s += part[g][tid];
        out[(size_t)b * 20 + tid] = s;
    }
}

// ---------------------------------------------------------------------------
extern "C" void kernel_launch(void* const* d_in, const int* in_sizes, int n_in,
                              void* d_out, int out_size, void* d_ws, size_t ws_size,
                              hipStream_t stream) {
    const float* x   = (const float*)d_in[0];
    const float* W_h = (const float*)d_in[1];
    const float* b_h = (const float*)d_in[2];
    const float* W_r = (const float*)d_in[3];
    const float* b_r = (const float*)d_in[4];
    const float* tau = (const float*)d_in[5];

    char* ws = (char*)d_ws;
    unsigned short* wfrag = (unsigned short*)(ws + OFF_WFRAG);
    float* cur  = (float*)(ws + OFF_CUR);
    ull*   msk  = (ull*)(ws + OFF_MASK);
    float* out  = (float*)d_out;

    wprep<<<22, 256, 0, stream>>>(W_h, wfrag);
    gemm_cur<<<4000, 256, 0, stream>>>(x, wfrag, b_h, cur);
    lif<<<NCL * 256, 64, 0, stream>>>(cur, msk);
    readout<<<256, 512, 0, stream>>>(msk, W_r, b_r, tau, out);
}